// Round 1
// baseline (1397.912 us; speedup 1.0000x reference)
//
#include <hip/hip_runtime.h>

#define CC 32
#define DIM 24
#define SP (DIM*DIM*DIM)     // 13824
#define NPTS 27
#define M3 81
#define OUTC 64
#define BATCH 2
#define PS 26                // padded spatial size
#define CN (CC*NPTS)         // 864

// ---------------- Kernel A: offset = conv3d_3x3(x, p_w) + p_b ----------------
// offset layout: [b, m, sp]  (m in [0,81), sp = i*576 + j*24 + k)
__global__ __launch_bounds__(256)
void offset_conv_kernel(const float* __restrict__ x,
                        const float* __restrict__ p_w,
                        const float* __restrict__ p_b,
                        float* __restrict__ offset) {
    int idx = blockIdx.x * blockDim.x + threadIdx.x;
    const int total = BATCH * M3 * SP;
    if (idx >= total) return;
    int sp = idx % SP;
    int m  = (idx / SP) % M3;
    int b  = idx / (SP * M3);
    int i = sp / 576, j = (sp / 24) % 24, k = sp % 24;

    float sum = p_b[m];
    const float* xb = x + (size_t)b * CC * SP;
    const float* wm = p_w + (size_t)m * CC * NPTS;
    for (int c = 0; c < CC; ++c) {
        const float* xc = xb + c * SP;
        const float* wc = wm + c * NPTS;
        #pragma unroll
        for (int di = 0; di < 3; ++di) {
            int ii = i + di - 1;
            if ((unsigned)ii >= (unsigned)DIM) continue;
            #pragma unroll
            for (int dj = 0; dj < 3; ++dj) {
                int jj = j + dj - 1;
                if ((unsigned)jj >= (unsigned)DIM) continue;
                #pragma unroll
                for (int dk = 0; dk < 3; ++dk) {
                    int kk = k + dk - 1;
                    if ((unsigned)kk >= (unsigned)DIM) continue;
                    sum += wc[di*9 + dj*3 + dk] * xc[ii*576 + jj*24 + kk];
                }
            }
        }
    }
    offset[idx] = sum;
}

// ------------- Kernel B: sample (trilinear, deformed) + project --------------
// One block (256 threads) per voxel (b, i, j, k).
__global__ __launch_bounds__(256)
void sample_project_kernel(const float* __restrict__ x,
                           const float* __restrict__ offset,
                           const float* __restrict__ conv_w,
                           float* __restrict__ out,     // [2, 64, SP]
                           float* __restrict__ p_out) { // [2, SP, 81]
    int vox = blockIdx.x;            // b*SP + sp
    int b = vox / SP, sp = vox % SP;
    int i = sp / 576, j = (sp / 24) % 24, k = sp % 24;
    int t = threadIdx.x;

    __shared__ float s_wlo[M3], s_whi[M3];
    __shared__ int   s_qlo[M3], s_qhi[M3];
    __shared__ float s_acc[CN];
    __shared__ float s_part[256];

    if (t < M3) {
        int ax = t / NPTS, n = t % NPTS;
        float pn;
        if (ax == 0)      pn = (float)(n / 9 - 1);
        else if (ax == 1) pn = (float)((n / 3) % 3 - 1);
        else              pn = (float)(n % 3 - 1);
        float p0 = (ax == 0) ? (float)(i + 1) : (ax == 1) ? (float)(j + 1) : (float)(k + 1);
        float p = p0 + pn + offset[((size_t)b * M3 + t) * SP + sp];
        float f = floorf(p);
        int qlo = (int)fminf(fmaxf(f,       0.f), (float)(PS - 1));
        int qhi = (int)fminf(fmaxf(f + 1.f, 0.f), (float)(PS - 1));
        // out-of-range snap: p < PAD(=1) or p > s-1-PAD(=24)  -> use floor
        bool oob = (p < 1.f) || (p > 24.f);
        float pa = oob ? f : p;
        float pm = fminf(fmaxf(pa, 0.f), (float)(PS - 1));
        s_qlo[t] = qlo;
        s_qhi[t] = qhi;
        s_wlo[t] = 1.f + ((float)qlo - pm);   // corner bit==0 weight
        s_whi[t] = 1.f - ((float)qhi - pm);   // corner bit==1 weight
        p_out[(size_t)(b * SP + sp) * M3 + t] = pm;
    }
    __syncthreads();

    // phase 2: acc[c*27+n] = trilinear-gathered x at point n, channel c
    const float* xb = x + (size_t)b * CC * SP;
    for (int item = t; item < CN; item += 256) {
        int c = item / NPTS, n = item % NPTS;
        const float* xc = xb + c * SP;
        int   q0[2] = { s_qlo[n],          s_qhi[n]          };
        float w0[2] = { s_wlo[n],          s_whi[n]          };
        int   q1[2] = { s_qlo[NPTS + n],   s_qhi[NPTS + n]   };
        float w1[2] = { s_wlo[NPTS + n],   s_whi[NPTS + n]   };
        int   q2[2] = { s_qlo[2*NPTS + n], s_qhi[2*NPTS + n] };
        float w2[2] = { s_wlo[2*NPTS + n], s_whi[2*NPTS + n] };
        float acc = 0.f;
        #pragma unroll
        for (int cx = 0; cx < 2; ++cx) {
            int ii = q0[cx] - 1;            // padded coord -> x coord
            #pragma unroll
            for (int cy = 0; cy < 2; ++cy) {
                int jj = q1[cy] - 1;
                float wxy = w0[cx] * w1[cy];
                #pragma unroll
                for (int cz = 0; cz < 2; ++cz) {
                    int kk = q2[cz] - 1;
                    float v = 0.f;
                    if ((unsigned)ii < (unsigned)DIM &&
                        (unsigned)jj < (unsigned)DIM &&
                        (unsigned)kk < (unsigned)DIM)
                        v = xc[ii*576 + jj*24 + kk];
                    acc += wxy * w2[cz] * v;
                }
            }
        }
        s_acc[item] = acc;
    }
    __syncthreads();

    // phase 3: out[o] = dot(conv_w[o, :864], s_acc)
    {
        int o = t & 63, part = t >> 6;      // 4 partial sums of 216 each
        const float* wrow = conv_w + (size_t)o * CN + part * 216;
        const float* arow = s_acc + part * 216;
        float s = 0.f;
        for (int q = 0; q < 216; ++q) s += wrow[q] * arow[q];
        s_part[t] = s;
    }
    __syncthreads();
    if (t < OUTC) {
        float r = s_part[t] + s_part[t + 64] + s_part[t + 128] + s_part[t + 192];
        out[((size_t)b * OUTC + t) * SP + sp] = r;
    }
}

extern "C" void kernel_launch(void* const* d_in, const int* in_sizes, int n_in,
                              void* d_out, int out_size, void* d_ws, size_t ws_size,
                              hipStream_t stream) {
    const float* x      = (const float*)d_in[0];
    const float* p_w    = (const float*)d_in[1];
    const float* p_b    = (const float*)d_in[2];
    const float* conv_w = (const float*)d_in[3];

    float* out_all = (float*)d_out;
    float* out_main = out_all;                               // [2,64,13824]
    float* p_out    = out_all + (size_t)BATCH * OUTC * SP;   // [2,13824,81]

    float* offset = (float*)d_ws;                            // [2,81,13824] = 8.96 MB

    {
        int total = BATCH * M3 * SP;
        int blocks = (total + 255) / 256;
        offset_conv_kernel<<<blocks, 256, 0, stream>>>(x, p_w, p_b, offset);
    }
    {
        int blocks = BATCH * SP;                             // 27648 voxels
        sample_project_kernel<<<blocks, 256, 0, stream>>>(x, offset, conv_w,
                                                          out_main, p_out);
    }
}

// Round 2
// 536.486 us; speedup vs baseline: 2.6057x; 2.6057x over previous
//
#include <hip/hip_runtime.h>

#define CC 32
#define DIM 24
#define SP (DIM*DIM*DIM)     // 13824
#define NPTS 27
#define M3 81
#define OUTC 64
#define BATCH 2
#define PS 26                // padded spatial size
#define CN (CC*NPTS)         // 864 = K

#define VBA 12               // voxels per block, kernel A
#define VBB 8                // voxels per block, kernel B

// ---------------- Kernel T: transpose weights into ws ----------------
// p_wT[k*81+m] = p_w[m*864+k];  conv_wT[k*64+o] = conv_w[o*864+k]
__global__ __launch_bounds__(256)
void transpose_w_kernel(const float* __restrict__ p_w,
                        const float* __restrict__ conv_w,
                        float* __restrict__ p_wT,
                        float* __restrict__ conv_wT) {
    int id = blockIdx.x * 256 + threadIdx.x;
    if (id < CN * M3) {
        int k = id / M3, m = id % M3;
        p_wT[id] = p_w[(size_t)m * CN + k];
    }
    if (id < CN * OUTC) {
        int k = id / OUTC, o = id % OUTC;
        conv_wT[id] = conv_w[(size_t)o * CN + k];
    }
}

// ---------------- Kernel A: offset = conv3d_3x3(x, p_w) + p_b (GEMM form) ---
// block: 12-voxel run along k axis. offset layout [b, m, sp].
__global__ __launch_bounds__(256)
void offset_gemm_kernel(const float* __restrict__ x,
                        const float* __restrict__ p_wT,
                        const float* __restrict__ p_b,
                        float* __restrict__ offset) {
    __shared__ float col[CN * VBA];          // 41472 B

    int bid = blockIdx.x;                    // 2304 = 2*24*24*2
    int r = bid % 2;
    int j = (bid / 2) % 24;
    int i = (bid / 48) % 24;
    int b = bid / 1152;
    int k0 = r * VBA;
    int sp0 = i * 576 + j * 24 + k0;
    int t = threadIdx.x;

    // --- im2col build: group g = c*9 + di*3 + dj loads a 14-long x row ---
    for (int g = t; g < CC * 9; g += 256) {
        int c = g / 9, dij = g % 9;
        int di = dij / 3, dj = dij % 3;
        int ii = i + di - 1, jj = j + dj - 1;
        bool rv = ((unsigned)ii < (unsigned)DIM) && ((unsigned)jj < (unsigned)DIM);
        const float* xr = x + ((size_t)(b * CC + c) * SP) + ii * 576 + jj * 24;
        float row[VBA + 2];
        #pragma unroll
        for (int u = 0; u < VBA + 2; ++u) {
            int kk = k0 - 1 + u;
            row[u] = (rv && (unsigned)kk < (unsigned)DIM) ? xr[kk] : 0.f;
        }
        int kbase = c * 27 + dij * 3;
        #pragma unroll
        for (int dk = 0; dk < 3; ++dk)
            for (int v = 0; v < VBA; ++v)
                col[(kbase + dk) * VBA + v] = row[v + dk];
    }
    __syncthreads();

    // --- GEMM: 81 x 864 @ 864 x 12 ---
    if (t < 243) {
        int m = t % M3, vg = t / M3;         // vg in 0..2, owns 4 voxels
        float bias = p_b[m];
        float4 acc = make_float4(bias, bias, bias, bias);
        const float* wp = p_wT + m;
        #pragma unroll 4
        for (int k = 0; k < CN; ++k) {
            float w = wp[k * M3];
            float4 cv = *(const float4*)&col[k * VBA + vg * 4];
            acc.x += w * cv.x; acc.y += w * cv.y;
            acc.z += w * cv.z; acc.w += w * cv.w;
        }
        *(float4*)&offset[((size_t)(b * M3 + m)) * SP + sp0 + vg * 4] = acc;
    }
}

// ------------- Kernel B: trilinear sample + project (GEMM form) --------------
// block: 8-voxel run along k axis.
__global__ __launch_bounds__(256)
void sample_gemm_kernel(const float* __restrict__ x,
                        const float* __restrict__ offset,
                        const float* __restrict__ conv_wT,
                        float* __restrict__ out,     // [2, 64, SP]
                        float* __restrict__ p_out) { // [2, SP, 81]
    __shared__ float s_f [M3 * VBB];         // 2592 B
    __shared__ float s_pm[M3 * VBB];         // 2592 B
    __shared__ int   s_cidx[8 * NPTS * VBB]; // 6912 B
    __shared__ float s_cw  [8 * NPTS * VBB]; // 6912 B
    __shared__ float col[CN * VBB];          // 27648 B

    int bid = blockIdx.x;                    // 3456 = 2*24*24*3
    int r = bid % 3;
    int j = (bid / 3) % 24;
    int i = (bid / 72) % 24;
    int b = bid / 1728;
    int k0 = r * VBB;
    int sp0 = i * 576 + j * 24 + k0;
    int t = threadIdx.x;

    // --- phase 1a: per (m, v) compute floor & snapped pm ---
    for (int it = t; it < M3 * VBB; it += 256) {
        int m = it / VBB, v = it % VBB;
        int ax = m / NPTS, n = m % NPTS;
        float pn = (ax == 0) ? (float)(n / 9 - 1)
                 : (ax == 1) ? (float)((n / 3) % 3 - 1)
                 :             (float)(n % 3 - 1);
        float p0 = (ax == 0) ? (float)(i + 1)
                 : (ax == 1) ? (float)(j + 1)
                 :             (float)(k0 + v + 1);
        float p = p0 + pn + offset[((size_t)(b * M3 + m)) * SP + sp0 + v];
        float f = floorf(p);
        bool oob = (p < 1.f) || (p > 24.f);
        float pa = oob ? f : p;
        float pm = fminf(fmaxf(pa, 0.f), (float)(PS - 1));
        s_f[it] = f;
        s_pm[it] = pm;
    }
    __syncthreads();

    // --- p_out writes, coalesced over m ---
    for (int it = t; it < M3 * VBB; it += 256) {
        int v = it / M3, m = it % M3;
        p_out[((size_t)(b * SP + sp0 + v)) * M3 + m] = s_pm[m * VBB + v];
    }

    // --- phase 1b: per (n, v) build 8 corner (index, weight) ---
    if (t < NPTS * VBB) {
        int n = t / VBB, v = t % VBB;
        int   ql[3], qh[3];
        float wl[3], wh[3];
        #pragma unroll
        for (int ax = 0; ax < 3; ++ax) {
            int idx = (ax * NPTS + n) * VBB + v;
            float f = s_f[idx], pm = s_pm[idx];
            int qlo = (int)fminf(fmaxf(f,       0.f), (float)(PS - 1));
            int qhi = (int)fminf(fmaxf(f + 1.f, 0.f), (float)(PS - 1));
            ql[ax] = qlo; qh[ax] = qhi;
            wl[ax] = 1.f + ((float)qlo - pm);
            wh[ax] = 1.f - ((float)qhi - pm);
        }
        #pragma unroll
        for (int cr = 0; cr < 8; ++cr) {
            int cx = (cr >> 2) & 1, cy = (cr >> 1) & 1, cz = cr & 1;
            int ii = (cx ? qh[0] : ql[0]) - 1;
            int jj = (cy ? qh[1] : ql[1]) - 1;
            int kk = (cz ? qh[2] : ql[2]) - 1;
            bool valid = ((unsigned)ii < (unsigned)DIM) &&
                         ((unsigned)jj < (unsigned)DIM) &&
                         ((unsigned)kk < (unsigned)DIM);
            float cw = (cx ? wh[0] : wl[0]) * (cy ? wh[1] : wl[1]) * (cz ? wh[2] : wl[2]);
            int nv = n * VBB + v;
            s_cidx[cr * (NPTS * VBB) + nv] = valid ? (ii * 576 + jj * 24 + kk) : -1;
            s_cw  [cr * (NPTS * VBB) + nv] = cw;
        }
    }
    __syncthreads();

    // --- phase 2: gather x at 8 corners -> col[c*27+n][v] ---
    for (int it = t; it < CC * NPTS * VBB; it += 256) {
        int c = it / (NPTS * VBB), nv = it % (NPTS * VBB);
        const float* xc = x + (size_t)(b * CC + c) * SP;
        float acc = 0.f;
        #pragma unroll
        for (int cr = 0; cr < 8; ++cr) {
            int   idx = s_cidx[cr * (NPTS * VBB) + nv];
            float cw  = s_cw  [cr * (NPTS * VBB) + nv];
            if (idx >= 0) acc += cw * xc[idx];
        }
        col[it] = acc;
    }
    __syncthreads();

    // --- phase 3: GEMM 64 x 864 @ 864 x 8 ---
    {
        int o = t & 63, vg = t >> 6;         // vg in 0..3, owns 2 voxels
        float2 acc = make_float2(0.f, 0.f);
        const float* wp = conv_wT + o;
        #pragma unroll 4
        for (int k = 0; k < CN; ++k) {
            float w = wp[k * OUTC];
            float2 cv = *(const float2*)&col[k * VBB + vg * 2];
            acc.x += w * cv.x; acc.y += w * cv.y;
        }
        *(float2*)&out[((size_t)(b * OUTC + o)) * SP + sp0 + vg * 2] = acc;
    }
}

extern "C" void kernel_launch(void* const* d_in, const int* in_sizes, int n_in,
                              void* d_out, int out_size, void* d_ws, size_t ws_size,
                              hipStream_t stream) {
    const float* x      = (const float*)d_in[0];
    const float* p_w    = (const float*)d_in[1];
    const float* p_b    = (const float*)d_in[2];
    const float* conv_w = (const float*)d_in[3];

    float* out_all = (float*)d_out;
    float* out_main = out_all;                               // [2,64,13824]
    float* p_out    = out_all + (size_t)BATCH * OUTC * SP;   // [2,13824,81]

    float* offset  = (float*)d_ws;                           // [2,81,13824]
    float* p_wT    = offset + (size_t)BATCH * M3 * SP;       // [864,81]
    float* conv_wT = p_wT + (size_t)CN * M3;                 // [864,64]

    {
        int total = CN * M3;                                 // max of the two
        transpose_w_kernel<<<(total + 255) / 256, 256, 0, stream>>>(p_w, conv_w,
                                                                    p_wT, conv_wT);
    }
    {
        int blocks = BATCH * 24 * 24 * (DIM / VBA);          // 2304
        offset_gemm_kernel<<<blocks, 256, 0, stream>>>(x, p_wT, p_b, offset);
    }
    {
        int blocks = BATCH * 24 * 24 * (DIM / VBB);          // 3456
        sample_gemm_kernel<<<blocks, 256, 0, stream>>>(x, offset, conv_wT,
                                                       out_main, p_out);
    }
}

// Round 3
// 379.251 us; speedup vs baseline: 3.6860x; 1.4146x over previous
//
#include <hip/hip_runtime.h>

#define CC 32
#define DIM 24
#define SP (DIM*DIM*DIM)     // 13824
#define NPTS 27
#define M3 81
#define OUTC 64
#define BATCH 2
#define PS 26                // padded spatial size
#define CN (CC*NPTS)         // 864 = K

#define VBA 12               // voxels per block, kernel A
#define VBB 8                // voxels per block, kernel B
#define NV (NPTS*VBB)        // 216

__device__ __forceinline__ unsigned short f2bf(float f) {
    unsigned u = __builtin_bit_cast(unsigned, f);
    return (unsigned short)((u + 0x7FFFu + ((u >> 16) & 1u)) >> 16);
}

// ---------------- Kernel T: transpose weights into ws ----------------
__global__ __launch_bounds__(256)
void transpose_w_kernel(const float* __restrict__ p_w,
                        const float* __restrict__ conv_w,
                        float* __restrict__ p_wT,
                        float* __restrict__ conv_wT) {
    int id = blockIdx.x * 256 + threadIdx.x;
    if (id < CN * M3) {
        int k = id / M3, m = id % M3;
        p_wT[id] = p_w[(size_t)m * CN + k];
    }
    if (id < CN * OUTC) {
        int k = id / OUTC, o = id % OUTC;
        conv_wT[id] = conv_w[(size_t)o * CN + k];
    }
}

// ---------------- Kernel A: offset = conv3d_3x3(x, p_w) + p_b (GEMM form) ---
// block: 12-voxel run along k axis. offset layout [b, m, sp]. Pure fp32.
__global__ __launch_bounds__(256)
void offset_gemm_kernel(const float* __restrict__ x,
                        const float* __restrict__ p_wT,
                        const float* __restrict__ p_b,
                        float* __restrict__ offset) {
    __shared__ float col[CN * VBA];          // 41472 B

    int bid = blockIdx.x;                    // 2304 = 2*24*24*2
    int r = bid % 2;
    int j = (bid / 2) % 24;
    int i = (bid / 48) % 24;
    int b = bid / 1152;
    int k0 = r * VBA;
    int sp0 = i * 576 + j * 24 + k0;
    int t = threadIdx.x;

    for (int g = t; g < CC * 9; g += 256) {
        int c = g / 9, dij = g % 9;
        int di = dij / 3, dj = dij % 3;
        int ii = i + di - 1, jj = j + dj - 1;
        bool rv = ((unsigned)ii < (unsigned)DIM) && ((unsigned)jj < (unsigned)DIM);
        const float* xr = x + ((size_t)(b * CC + c) * SP) + ii * 576 + jj * 24;
        float row[VBA + 2];
        #pragma unroll
        for (int u = 0; u < VBA + 2; ++u) {
            int kk = k0 - 1 + u;
            row[u] = (rv && (unsigned)kk < (unsigned)DIM) ? xr[kk] : 0.f;
        }
        int kbase = c * 27 + dij * 3;
        #pragma unroll
        for (int dk = 0; dk < 3; ++dk)
            for (int v = 0; v < VBA; ++v)
                col[(kbase + dk) * VBA + v] = row[v + dk];
    }
    __syncthreads();

    if (t < 243) {
        int m = t % M3, vg = t / M3;         // vg in 0..2, owns 4 voxels
        float bias = p_b[m];
        float4 acc = make_float4(bias, bias, bias, bias);
        const float* wp = p_wT + m;
        #pragma unroll 4
        for (int k = 0; k < CN; ++k) {
            float w = wp[k * M3];
            float4 cv = *(const float4*)&col[k * VBA + vg * 4];
            acc.x += w * cv.x; acc.y += w * cv.y;
            acc.z += w * cv.z; acc.w += w * cv.w;
        }
        *(float4*)&offset[((size_t)(b * M3 + m)) * SP + sp0 + vg * 4] = acc;
    }
}

// ------------- Kernel B: trilinear sample + project (GEMM form) --------------
// block: 8-voxel run along k. LDS = 6.9KB corners + 13.8KB bf16 column.
__global__ __launch_bounds__(256, 8)
void sample_gemm_kernel(const float* __restrict__ x,
                        const float* __restrict__ offset,
                        const float* __restrict__ conv_wT,
                        float* __restrict__ out,     // [2, 64, SP]
                        float* __restrict__ p_out) { // [2, SP, 81]
    __shared__ unsigned s_corner[8][NV];          // 6912 B: idx<<16 | bf16(cw)
    __shared__ unsigned short col16[CN * VBB];    // 13824 B

    int bid = blockIdx.x;                    // 3456 = 2*24*24*3
    int r = bid % 3;
    int j = (bid / 3) % 24;
    int i = (bid / 72) % 24;
    int b = bid / 1728;
    int k0 = r * VBB;
    int sp0 = i * 576 + j * 24 + k0;
    int t = threadIdx.x;

    // --- phase 1: per (n, v): positions, p_out, 8 packed corners ---
    if (t < NV) {
        int n = t / VBB, v = t % VBB;
        int ql[3], qh[3];
        float wl[3], wh[3];
        int pnx = n / 9 - 1, pny = (n / 3) % 3 - 1, pnz = n % 3 - 1;
        float p0a[3] = { (float)(i + 1 + pnx),
                         (float)(j + 1 + pny),
                         (float)(k0 + v + 1 + pnz) };
        #pragma unroll
        for (int ax = 0; ax < 3; ++ax) {
            int m = ax * NPTS + n;
            float p = p0a[ax] + offset[((size_t)(b * M3 + m)) * SP + sp0 + v];
            float f = floorf(p);
            int qlo = (int)fminf(fmaxf(f,       0.f), 25.f);
            int qhi = (int)fminf(fmaxf(f + 1.f, 0.f), 25.f);
            bool oob = (p < 1.f) || (p > 24.f);
            float pa = oob ? f : p;
            float pm = fminf(fmaxf(pa, 0.f), 25.f);
            ql[ax] = qlo; qh[ax] = qhi;
            wl[ax] = 1.f + ((float)qlo - pm);
            wh[ax] = 1.f - ((float)qhi - pm);
            p_out[((size_t)(b * SP + sp0 + v)) * M3 + m] = pm;
        }
        #pragma unroll
        for (int cr = 0; cr < 8; ++cr) {
            int ii = ((cr & 4) ? qh[0] : ql[0]) - 1;
            int jj = ((cr & 2) ? qh[1] : ql[1]) - 1;
            int kk = ((cr & 1) ? qh[2] : ql[2]) - 1;
            float cw = ((cr & 4) ? wh[0] : wl[0]) *
                       ((cr & 2) ? wh[1] : wl[1]) *
                       ((cr & 1) ? wh[2] : wl[2]);
            bool valid = ((unsigned)ii < (unsigned)DIM) &&
                         ((unsigned)jj < (unsigned)DIM) &&
                         ((unsigned)kk < (unsigned)DIM);
            unsigned idx = (unsigned)(ii * 576 + jj * 24 + kk);
            s_corner[cr][t] = valid ? ((idx << 16) | (unsigned)f2bf(cw)) : 0u;
        }
    }
    __syncthreads();

    // --- phase 2: gather 8 corners -> col16[k*8+v] (bf16) ---
    const float* xb = x + (size_t)b * CC * SP;
    for (int it = t; it < CN * VBB; it += 256) {
        int c = it / NV;
        int nv = it - c * NV;
        const float* xc = xb + c * SP;
        float acc = 0.f;
        #pragma unroll
        for (int cr = 0; cr < 8; ++cr) {
            unsigned uu = s_corner[cr][nv];
            float cw = __builtin_bit_cast(float, uu << 16);
            acc += cw * xc[uu >> 16];
        }
        col16[it] = f2bf(acc);
    }
    __syncthreads();

    // --- phase 3: GEMM 64 x 864 @ 864 x 8 (col broadcast from LDS) ---
    {
        int o = t & 63, vg = t >> 6;         // vg owns 2 voxels
        const float* wp = conv_wT + o;
        const unsigned* colp = (const unsigned*)col16 + vg;
        float accx = 0.f, accy = 0.f;
        #pragma unroll 8
        for (int k = 0; k < CN; ++k) {
            float w = wp[(size_t)k * OUTC];
            unsigned u = colp[k * 4];
            accx += w * __builtin_bit_cast(float, u << 16);
            accy += w * __builtin_bit_cast(float, u & 0xFFFF0000u);
        }
        *(float2*)&out[((size_t)(b * OUTC + o)) * SP + sp0 + vg * 2] =
            make_float2(accx, accy);
    }
}

extern "C" void kernel_launch(void* const* d_in, const int* in_sizes, int n_in,
                              void* d_out, int out_size, void* d_ws, size_t ws_size,
                              hipStream_t stream) {
    const float* x      = (const float*)d_in[0];
    const float* p_w    = (const float*)d_in[1];
    const float* p_b    = (const float*)d_in[2];
    const float* conv_w = (const float*)d_in[3];

    float* out_all = (float*)d_out;
    float* out_main = out_all;                               // [2,64,13824]
    float* p_out    = out_all + (size_t)BATCH * OUTC * SP;   // [2,13824,81]

    float* offset  = (float*)d_ws;                           // [2,81,13824]
    float* p_wT    = offset + (size_t)BATCH * M3 * SP;       // [864,81]
    float* conv_wT = p_wT + (size_t)CN * M3;                 // [864,64]

    {
        int total = CN * M3;
        transpose_w_kernel<<<(total + 255) / 256, 256, 0, stream>>>(p_w, conv_w,
                                                                    p_wT, conv_wT);
    }
    {
        int blocks = BATCH * 24 * 24 * (DIM / VBA);          // 2304
        offset_gemm_kernel<<<blocks, 256, 0, stream>>>(x, p_wT, p_b, offset);
    }
    {
        int blocks = BATCH * 24 * 24 * (DIM / VBB);          // 3456
        sample_gemm_kernel<<<blocks, 256, 0, stream>>>(x, offset, conv_wT,
                                                       out_main, p_out);
    }
}

// Round 4
// 305.780 us; speedup vs baseline: 4.5716x; 1.2403x over previous
//
#include <hip/hip_runtime.h>

#define CC 32
#define DIM 24
#define SP (DIM*DIM*DIM)     // 13824
#define NPTS 27
#define M3 81
#define OUTC 64
#define BATCH 2
#define PS 26                // padded spatial size
#define CN (CC*NPTS)         // 864 = K

#define VBA 12               // voxels per block, kernel A
#define VBB 16               // voxels per block, kernel B (MFMA N)
#define NV (NPTS*VBB)        // 432
#define CPAD 896             // padded col row (multiple of 64 for XOR swizzle)

typedef __attribute__((ext_vector_type(8))) short short8;
typedef __attribute__((ext_vector_type(4))) float f32x4;

__device__ __forceinline__ unsigned short f2bf(float f) {
    unsigned u = __builtin_bit_cast(unsigned, f);
    return (unsigned short)((u + 0x7FFFu + ((u >> 16) & 1u)) >> 16);
}

// ---------------- Kernel T: weight prep ----------------
// p_wT[k*81+m] = p_w[m*864+k] (fp32);  conv_wbf[o*864+k] = bf16(conv_w[o*864+k])
__global__ __launch_bounds__(256)
void prep_w_kernel(const float* __restrict__ p_w,
                   const float* __restrict__ conv_w,
                   float* __restrict__ p_wT,
                   unsigned short* __restrict__ conv_wbf) {
    int id = blockIdx.x * 256 + threadIdx.x;
    if (id < CN * M3) {
        int k = id / M3, m = id % M3;
        p_wT[id] = p_w[(size_t)m * CN + k];
    }
    if (id < CN * OUTC) {
        conv_wbf[id] = f2bf(conv_w[id]);
    }
}

// ---------------- Kernel A: offset = conv3d_3x3(x, p_w) + p_b (fp32 GEMM) ---
__global__ __launch_bounds__(256)
void offset_gemm_kernel(const float* __restrict__ x,
                        const float* __restrict__ p_wT,
                        const float* __restrict__ p_b,
                        float* __restrict__ offset) {
    __shared__ float col[CN * VBA];          // 41472 B

    int bid = blockIdx.x;                    // 2304 = 2*24*24*2
    int r = bid % 2;
    int j = (bid / 2) % 24;
    int i = (bid / 48) % 24;
    int b = bid / 1152;
    int k0 = r * VBA;
    int sp0 = i * 576 + j * 24 + k0;
    int t = threadIdx.x;

    for (int g = t; g < CC * 9; g += 256) {
        int c = g / 9, dij = g % 9;
        int di = dij / 3, dj = dij % 3;
        int ii = i + di - 1, jj = j + dj - 1;
        bool rv = ((unsigned)ii < (unsigned)DIM) && ((unsigned)jj < (unsigned)DIM);
        const float* xr = x + ((size_t)(b * CC + c) * SP) + ii * 576 + jj * 24;
        float row[VBA + 2];
        #pragma unroll
        for (int u = 0; u < VBA + 2; ++u) {
            int kk = k0 - 1 + u;
            row[u] = (rv && (unsigned)kk < (unsigned)DIM) ? xr[kk] : 0.f;
        }
        int kbase = c * 27 + dij * 3;
        #pragma unroll
        for (int dk = 0; dk < 3; ++dk)
            for (int v = 0; v < VBA; ++v)
                col[(kbase + dk) * VBA + v] = row[v + dk];
    }
    __syncthreads();

    if (t < 243) {
        int m = t % M3, vg = t / M3;
        float bias = p_b[m];
        float4 acc = make_float4(bias, bias, bias, bias);
        const float* wp = p_wT + m;
        #pragma unroll 4
        for (int k = 0; k < CN; ++k) {
            float w = wp[k * M3];
            float4 cv = *(const float4*)&col[k * VBA + vg * 4];
            acc.x += w * cv.x; acc.y += w * cv.y;
            acc.z += w * cv.z; acc.w += w * cv.w;
        }
        *(float4*)&offset[((size_t)(b * M3 + m)) * SP + sp0 + vg * 4] = acc;
    }
}

// ------------- Kernel B: trilinear sample + MFMA projection --------------
// 16 flat voxels per block; col[v][k] bf16 in LDS (row 896, XOR-swizzled);
// phase 3: out[64x16] = conv_w[64x864] @ col[864x16] via mfma 16x16x32 bf16.
__global__ __launch_bounds__(256, 5)
void sample_gemm_kernel(const float* __restrict__ x,
                        const float* __restrict__ offset,
                        const unsigned short* __restrict__ conv_wbf,
                        float* __restrict__ out,     // [2, 64, SP]
                        float* __restrict__ p_out) { // [2, SP, 81]
    __shared__ unsigned short col[VBB * CPAD];       // 28672 B

    int vox0 = blockIdx.x * VBB;             // 1728 blocks
    int b = vox0 / SP;
    int sp0 = vox0 % SP;
    int t = threadIdx.x;

    const float* xb = x + (size_t)b * CC * SP;

    // --- phase 1+2: per (n, v): corners in regs, gather 32 channels -> col ---
    for (int it = t; it < NV; it += 256) {
        int v = it & 15, n = it >> 4;
        int sp = sp0 + v;
        int i = sp / 576, j = (sp / 24) % 24, k = sp % 24;

        int pnx = n / 9 - 1, pny = (n / 3) % 3 - 1, pnz = n % 3 - 1;
        float p0a[3] = { (float)(i + 1 + pnx),
                         (float)(j + 1 + pny),
                         (float)(k + 1 + pnz) };
        int ql[3], qh[3];
        float wl[3], wh[3];
        #pragma unroll
        for (int ax = 0; ax < 3; ++ax) {
            int m = ax * NPTS + n;
            float p = p0a[ax] + offset[((size_t)(b * M3 + m)) * SP + sp];
            float f = floorf(p);
            int qlo = (int)fminf(fmaxf(f,       0.f), 25.f);
            int qhi = (int)fminf(fmaxf(f + 1.f, 0.f), 25.f);
            bool oob = (p < 1.f) || (p > 24.f);
            float pa = oob ? f : p;
            float pm = fminf(fmaxf(pa, 0.f), 25.f);
            ql[ax] = qlo; qh[ax] = qhi;
            wl[ax] = 1.f + ((float)qlo - pm);
            wh[ax] = 1.f - ((float)qhi - pm);
            p_out[((size_t)(b * SP + sp)) * M3 + m] = pm;
        }

        int   idxr[8];
        float wr[8];
        #pragma unroll
        for (int cr = 0; cr < 8; ++cr) {
            int ii = ((cr & 4) ? qh[0] : ql[0]) - 1;
            int jj = ((cr & 2) ? qh[1] : ql[1]) - 1;
            int kk = ((cr & 1) ? qh[2] : ql[2]) - 1;
            bool valid = ((unsigned)ii < (unsigned)DIM) &&
                         ((unsigned)jj < (unsigned)DIM) &&
                         ((unsigned)kk < (unsigned)DIM);
            float cw = ((cr & 4) ? wh[0] : wl[0]) *
                       ((cr & 2) ? wh[1] : wl[1]) *
                       ((cr & 1) ? wh[2] : wl[2]);
            idxr[cr] = valid ? (ii * 576 + jj * 24 + kk) : 0;
            wr[cr]   = valid ? cw : 0.f;
        }

        int sv = (v & 7) << 3;
        unsigned short* crow = col + v * CPAD;
        for (int c = 0; c < CC; ++c) {
            const float* xc = xb + (size_t)c * SP;
            float acc = 0.f;
            #pragma unroll
            for (int cr = 0; cr < 8; ++cr)
                acc += wr[cr] * xc[idxr[cr]];
            crow[(c * NPTS + n) ^ sv] = f2bf(acc);
        }
    }
    __syncthreads();

    // --- phase 3: MFMA GEMM 64 x 864 @ 864 x 16 ---
    {
        int mt = t >> 6;                      // wave -> M tile (16 rows)
        int l = t & 63;
        int lr = l & 15;                      // A row / B col (voxel)
        int g = l >> 4;
        int sv = (lr & 7) << 3;

        const short8* ap =
            (const short8*)(conv_wbf + ((size_t)(mt * 16 + lr)) * CN + g * 8);
        const unsigned short* bp = col + lr * CPAD;

        f32x4 acc = {0.f, 0.f, 0.f, 0.f};
        #pragma unroll 3
        for (int kb = 0; kb < CN / 32; ++kb) {
            short8 a = ap[kb * 4];
            short8 bb = *(const short8*)&bp[(kb * 32 + g * 8) ^ sv];
            acc = __builtin_amdgcn_mfma_f32_16x16x32_bf16(a, bb, acc, 0, 0, 0);
        }
        float* op = out + ((size_t)(b * OUTC + mt * 16 + g * 4)) * SP + sp0 + lr;
        #pragma unroll
        for (int r = 0; r < 4; ++r)
            op[(size_t)r * SP] = acc[r];
    }
}

extern "C" void kernel_launch(void* const* d_in, const int* in_sizes, int n_in,
                              void* d_out, int out_size, void* d_ws, size_t ws_size,
                              hipStream_t stream) {
    const float* x      = (const float*)d_in[0];
    const float* p_w    = (const float*)d_in[1];
    const float* p_b    = (const float*)d_in[2];
    const float* conv_w = (const float*)d_in[3];

    float* out_all = (float*)d_out;
    float* out_main = out_all;                               // [2,64,13824]
    float* p_out    = out_all + (size_t)BATCH * OUTC * SP;   // [2,13824,81]

    float* offset          = (float*)d_ws;                   // [2,81,13824]
    float* p_wT            = offset + (size_t)BATCH * M3 * SP;
    unsigned short* conv_wbf = (unsigned short*)(p_wT + (size_t)CN * M3);

    {
        int total = CN * M3;                                 // 69984 (covers both)
        prep_w_kernel<<<(total + 255) / 256, 256, 0, stream>>>(p_w, conv_w,
                                                               p_wT, conv_wbf);
    }
    {
        int blocks = BATCH * 24 * 24 * (DIM / VBA);          // 2304
        offset_gemm_kernel<<<blocks, 256, 0, stream>>>(x, p_wT, p_b, offset);
    }
    {
        int blocks = BATCH * SP / VBB;                       // 1728
        sample_gemm_kernel<<<blocks, 256, 0, stream>>>(x, offset, conv_wbf,
                                                       out_main, p_out);
    }
}

// Round 5
// 159.446 us; speedup vs baseline: 8.7673x; 1.9178x over previous
//
#include <hip/hip_runtime.h>

#define CC 32
#define DIM 24
#define SP (DIM*DIM*DIM)     // 13824
#define NPTS 27
#define M3 81
#define OUTC 64
#define BATCH 2
#define PS 26                // padded spatial size
#define CN (CC*NPTS)         // 864 = K

#define VBA 12               // voxels per block, kernel A
#define VBB 16               // voxels per block, kernel B (MFMA N)
#define NV (NPTS*VBB)        // 432
#define CPAD 896             // padded col row (for XOR swizzle overflow)
#define MP 84                // padded M for offset GEMM (81 -> 84)

typedef __attribute__((ext_vector_type(8))) short short8;
typedef __attribute__((ext_vector_type(4))) float f32x4;

__device__ __forceinline__ unsigned short f2bf(float f) {
    unsigned u = __builtin_bit_cast(unsigned, f);
    return (unsigned short)((u + 0x7FFFu + ((u >> 16) & 1u)) >> 16);
}

// ---------------- Kernel T1: weight prep ----------------
// p_wTP[k*84+m] = p_w[m*864+k] (fp32, zero-padded m 81..83)
// conv_wbf[o*864 + n*32+c] = bf16(conv_w[o*864 + c*27+n])   (K-permuted)
__global__ __launch_bounds__(256)
void prep_w_kernel(const float* __restrict__ p_w,
                   const float* __restrict__ conv_w,
                   float* __restrict__ p_wTP,
                   unsigned short* __restrict__ conv_wbf) {
    int id = blockIdx.x * 256 + threadIdx.x;
    if (id < CN * MP) {
        int k = id / MP, m = id % MP;
        p_wTP[id] = (m < M3) ? p_w[(size_t)m * CN + k] : 0.f;
    }
    if (id < CN * OUTC) {
        int o = id / CN, kp = id % CN;
        int n = kp >> 5, c = kp & 31;
        conv_wbf[id] = f2bf(conv_w[(size_t)o * CN + c * NPTS + n]);
    }
}

// ---------------- Kernel T2: x -> x_t[b][sp][c] (bf16, channel-minor) -------
__global__ __launch_bounds__(256)
void transpose_x_kernel(const float* __restrict__ x,
                        unsigned short* __restrict__ x_t) {
    __shared__ float tile[CC][65];
    int b = blockIdx.x / 216;                // 13824/64 = 216 blocks per batch
    int sp0 = (blockIdx.x % 216) * 64;
    const float* xb = x + (size_t)b * CC * SP;
    for (int it = threadIdx.x; it < CC * 64; it += 256) {
        int c = it >> 6, s = it & 63;
        tile[c][s] = xb[(size_t)c * SP + sp0 + s];
    }
    __syncthreads();
    unsigned short* xtb = x_t + (size_t)b * SP * CC;
    for (int it = threadIdx.x; it < CC * 64; it += 256) {
        int s = it >> 5, c = it & 31;
        xtb[(size_t)(sp0 + s) * CC + c] = f2bf(tile[c][s]);
    }
}

// ---------------- Kernel A: offset conv as fp32 GEMM, 4-wave K-split --------
__global__ __launch_bounds__(256, 3)
void offset_gemm_kernel(const float* __restrict__ x,
                        const float* __restrict__ p_wTP,
                        const float* __restrict__ p_b,
                        float* __restrict__ offset) {
    __shared__ float col[CN * VBA];          // 41472 B; reused as partials

    int bid = blockIdx.x;                    // 2304 = 2*24*24*2
    int r = bid % 2;
    int j = (bid / 2) % 24;
    int i = (bid / 48) % 24;
    int b = bid / 1152;
    int k0 = r * VBA;
    int sp0 = i * 576 + j * 24 + k0;
    int t = threadIdx.x;

    // --- im2col: col[k][v], k = c*27 + di*9 + dj*3 + dk ---
    for (int g = t; g < CC * 9; g += 256) {
        int c = g / 9, dij = g % 9;
        int di = dij / 3, dj = dij % 3;
        int ii = i + di - 1, jj = j + dj - 1;
        bool rv = ((unsigned)ii < (unsigned)DIM) && ((unsigned)jj < (unsigned)DIM);
        const float* xr = x + ((size_t)(b * CC + c) * SP) + ii * 576 + jj * 24;
        float row[VBA + 2];
        #pragma unroll
        for (int u = 0; u < VBA + 2; ++u) {
            int kk = k0 - 1 + u;
            row[u] = (rv && (unsigned)kk < (unsigned)DIM) ? xr[kk] : 0.f;
        }
        int kbase = c * 27 + dij * 3;
        #pragma unroll
        for (int dk = 0; dk < 3; ++dk)
            for (int v = 0; v < VBA; ++v)
                col[(kbase + dk) * VBA + v] = row[v + dk];
    }
    __syncthreads();

    // --- GEMM: wave w handles k in [w*216,(w+1)*216); lane tile 4m x 4v ---
    int w = t >> 6, l = t & 63;
    int mt = l / 3, vt = l % 3;              // mt 0..20 (l<63), vt 0..2
    float acc[4][4];
    #pragma unroll
    for (int a = 0; a < 4; ++a)
        #pragma unroll
        for (int bq = 0; bq < 4; ++bq) acc[a][bq] = 0.f;

    if (l < 63) {
        int kbase = w * 216;
        const float* wp = p_wTP + (size_t)kbase * MP + mt * 4;
        const float* cp = col + kbase * VBA + vt * 4;
        for (int kk = 0; kk < 216; ++kk) {
            float4 wv = *(const float4*)(wp + kk * MP);
            float4 cv = *(const float4*)(cp + kk * VBA);
            acc[0][0] += wv.x * cv.x; acc[0][1] += wv.x * cv.y;
            acc[0][2] += wv.x * cv.z; acc[0][3] += wv.x * cv.w;
            acc[1][0] += wv.y * cv.x; acc[1][1] += wv.y * cv.y;
            acc[1][2] += wv.y * cv.z; acc[1][3] += wv.y * cv.w;
            acc[2][0] += wv.z * cv.x; acc[2][1] += wv.z * cv.y;
            acc[2][2] += wv.z * cv.z; acc[2][3] += wv.z * cv.w;
            acc[3][0] += wv.w * cv.x; acc[3][1] += wv.w * cv.y;
            acc[3][2] += wv.w * cv.z; acc[3][3] += wv.w * cv.w;
        }
    }
    __syncthreads();                          // all col reads done

    // --- partials into reused LDS: part[w][m(84)][v(12)] = 16128 B ---
    float* part = col;
    if (l < 63) {
        #pragma unroll
        for (int a = 0; a < 4; ++a) {
            float4 pv = make_float4(acc[a][0], acc[a][1], acc[a][2], acc[a][3]);
            *(float4*)&part[((w * MP) + mt * 4 + a) * VBA + vt * 4] = pv;
        }
    }
    __syncthreads();

    // --- 4-way reduce + bias + store ---
    if (t < 243) {
        int m = t % M3, vg = t / M3;         // vg 0..2
        float4 s = make_float4(0.f, 0.f, 0.f, 0.f);
        #pragma unroll
        for (int ww = 0; ww < 4; ++ww) {
            float4 pv = *(const float4*)&part[((ww * MP) + m) * VBA + vg * 4];
            s.x += pv.x; s.y += pv.y; s.z += pv.z; s.w += pv.w;
        }
        float bias = p_b[m];
        s.x += bias; s.y += bias; s.z += bias; s.w += bias;
        *(float4*)&offset[((size_t)(b * M3 + m)) * SP + sp0 + vg * 4] = s;
    }
}

// ------------- Kernel B: trilinear sample (x_t gather) + MFMA projection ----
__global__ __launch_bounds__(256, 4)
void sample_gemm_kernel(const unsigned short* __restrict__ x_t,
                        const float* __restrict__ offset,
                        const unsigned short* __restrict__ conv_wbf,
                        float* __restrict__ out,     // [2, 64, SP]
                        float* __restrict__ p_out) { // [2, SP, 81]
    __shared__ unsigned short col[VBB * CPAD];       // 28672 B, k' = n*32+c

    int vox0 = blockIdx.x * VBB;             // 1728 blocks
    int b = vox0 / SP;
    int sp0 = vox0 % SP;
    int t = threadIdx.x;

    const unsigned short* xtb = x_t + (size_t)b * SP * CC;

    // --- phase 1+2: per (n, v): corners in regs, gather 32 channels -> col ---
    for (int it = t; it < NV; it += 256) {
        int v = it & 15, n = it >> 4;
        int sp = sp0 + v;
        int i = sp / 576, j = (sp / 24) % 24, k = sp % 24;

        int pnx = n / 9 - 1, pny = (n / 3) % 3 - 1, pnz = n % 3 - 1;
        float p0a[3] = { (float)(i + 1 + pnx),
                         (float)(j + 1 + pny),
                         (float)(k + 1 + pnz) };
        int ql[3], qh[3];
        float wl[3], wh[3];
        #pragma unroll
        for (int ax = 0; ax < 3; ++ax) {
            int m = ax * NPTS + n;
            float p = p0a[ax] + offset[((size_t)(b * M3 + m)) * SP + sp];
            float f = floorf(p);
            int qlo = (int)fminf(fmaxf(f,       0.f), 25.f);
            int qhi = (int)fminf(fmaxf(f + 1.f, 0.f), 25.f);
            bool oob = (p < 1.f) || (p > 24.f);
            float pa = oob ? f : p;
            float pm = fminf(fmaxf(pa, 0.f), 25.f);
            ql[ax] = qlo; qh[ax] = qhi;
            wl[ax] = 1.f + ((float)qlo - pm);
            wh[ax] = 1.f - ((float)qhi - pm);
            p_out[((size_t)(b * SP + sp)) * M3 + m] = pm;
        }

        int   idxr[8];                        // element offset into xtb
        float wr[8];
        #pragma unroll
        for (int cr = 0; cr < 8; ++cr) {
            int ii = ((cr & 4) ? qh[0] : ql[0]) - 1;
            int jj = ((cr & 2) ? qh[1] : ql[1]) - 1;
            int kk = ((cr & 1) ? qh[2] : ql[2]) - 1;
            bool valid = ((unsigned)ii < (unsigned)DIM) &&
                         ((unsigned)jj < (unsigned)DIM) &&
                         ((unsigned)kk < (unsigned)DIM);
            float cw = ((cr & 4) ? wh[0] : wl[0]) *
                       ((cr & 2) ? wh[1] : wl[1]) *
                       ((cr & 1) ? wh[2] : wl[2]);
            idxr[cr] = valid ? (ii * 576 + jj * 24 + kk) * CC : 0;
            wr[cr]   = valid ? cw : 0.f;
        }

        int sv = (v & 7) << 3;
        unsigned short* crow = col + v * CPAD;
        #pragma unroll
        for (int half = 0; half < 2; ++half) {
            float acc[16];
            #pragma unroll
            for (int q = 0; q < 16; ++q) acc[q] = 0.f;
            #pragma unroll
            for (int cr = 0; cr < 8; ++cr) {
                const unsigned* s = (const unsigned*)(xtb + idxr[cr] + half * 16);
                float wc = wr[cr];
                #pragma unroll
                for (int q2 = 0; q2 < 8; ++q2) {
                    unsigned u = s[q2];
                    acc[2 * q2]     += wc * __builtin_bit_cast(float, u << 16);
                    acc[2 * q2 + 1] += wc * __builtin_bit_cast(float, u & 0xFFFF0000u);
                }
            }
            #pragma unroll
            for (int q8 = 0; q8 < 2; ++q8) {
                short8 pk;
                #pragma unroll
                for (int e = 0; e < 8; ++e)
                    pk[e] = (short)f2bf(acc[q8 * 8 + e]);
                *(short8*)&crow[(n * 32 + half * 16 + q8 * 8) ^ sv] = pk;
            }
        }
    }
    __syncthreads();

    // --- phase 3: MFMA GEMM 64 x 864 @ 864 x 16 (K-permuted both sides) ---
    {
        int mt = t >> 6;                      // wave -> M tile (16 rows)
        int l = t & 63;
        int lr = l & 15;                      // A row / B col (voxel)
        int g = l >> 4;
        int sv = (lr & 7) << 3;

        const short8* ap =
            (const short8*)(conv_wbf + ((size_t)(mt * 16 + lr)) * CN + g * 8);
        const unsigned short* bp = col + lr * CPAD;

        f32x4 acc = {0.f, 0.f, 0.f, 0.f};
        #pragma unroll 3
        for (int kb = 0; kb < CN / 32; ++kb) {
            short8 a = ap[kb * 4];
            short8 bb = *(const short8*)&bp[(kb * 32 + g * 8) ^ sv];
            acc = __builtin_amdgcn_mfma_f32_16x16x32_bf16(a, bb, acc, 0, 0, 0);
        }
        float* op = out + ((size_t)(b * OUTC + mt * 16 + g * 4)) * SP + sp0 + lr;
        #pragma unroll
        for (int rr = 0; rr < 4; ++rr)
            op[(size_t)rr * SP] = acc[rr];
    }
}

extern "C" void kernel_launch(void* const* d_in, const int* in_sizes, int n_in,
                              void* d_out, int out_size, void* d_ws, size_t ws_size,
                              hipStream_t stream) {
    const float* x      = (const float*)d_in[0];
    const float* p_w    = (const float*)d_in[1];
    const float* p_b    = (const float*)d_in[2];
    const float* conv_w = (const float*)d_in[3];

    float* out_all = (float*)d_out;
    float* out_main = out_all;                               // [2,64,13824]
    float* p_out    = out_all + (size_t)BATCH * OUTC * SP;   // [2,13824,81]

    float* offset          = (float*)d_ws;                   // [2,81,13824] 8.96MB
    float* p_wTP           = offset + (size_t)BATCH * M3 * SP;       // 864*84 f32
    unsigned short* conv_wbf = (unsigned short*)(p_wTP + (size_t)CN * MP); // 864*64 bf16
    unsigned short* x_t    = conv_wbf + (size_t)CN * OUTC;   // [2,13824,32] bf16

    {
        int total = CN * MP;                                 // 72576 covers both
        prep_w_kernel<<<(total + 255) / 256, 256, 0, stream>>>(p_w, conv_w,
                                                               p_wTP, conv_wbf);
    }
    {
        int blocks = BATCH * (SP / 64);                      // 432
        transpose_x_kernel<<<blocks, 256, 0, stream>>>(x, x_t);
    }
    {
        int blocks = BATCH * 24 * 24 * (DIM / VBA);          // 2304
        offset_gemm_kernel<<<blocks, 256, 0, stream>>>(x, p_wTP, p_b, offset);
    }
    {
        int blocks = BATCH * SP / VBB;                       // 1728
        sample_gemm_kernel<<<blocks, 256, 0, stream>>>(x_t, offset, conv_wbf,
                                                       out_main, p_out);
    }
}